// Round 1
// baseline (137.028 us; speedup 1.0000x reference)
//
#include <hip/hip_runtime.h>

#define DIM 256
#define NG 64
#define S_TILE 8
#define NCHUNK 8
#define BLOCK 128

// ---------- prep kernels: counting sort of samples by gaussian id ----------

__global__ void zero_counts_kernel(int* counts) {
    counts[threadIdx.x] = 0;  // launched with NG threads
}

__global__ void count_pos_kernel(const int* __restrict__ k, int* counts,
                                 int* pos, int batch) {
    int b = blockIdx.x * blockDim.x + threadIdx.x;
    if (b < batch) {
        int g = k[b];
        pos[b] = atomicAdd(&counts[g], 1);
    }
}

__global__ void prefix_kernel(const int* __restrict__ counts, int* offsets) {
    // NG=64 values; serial scan on one thread is nanoseconds
    int acc = 0;
    for (int g = 0; g < NG; ++g) {
        offsets[g] = acc;
        acc += counts[g];
    }
}

__global__ void scatter_kernel(const int* __restrict__ k,
                               const int* __restrict__ offsets,
                               const int* __restrict__ pos, int* list,
                               int batch) {
    int b = blockIdx.x * blockDim.x + threadIdx.x;
    if (b < batch) {
        int g = k[b];
        list[offsets[g] + pos[b]] = b;
    }
}

// ---------- main kernel: per-gaussian batched matvec ----------
// grid = NG * NCHUNK blocks, BLOCK=128 threads.
// Block (g, c) processes sample tiles c*S_TILE, c*S_TILE + NCHUNK*S_TILE, ...
// of gaussian g's bucket. Each thread owns output dims d and d+128 and
// register-blocks S_TILE samples; eps tile staged in LDS (broadcast reads).

__global__ __launch_bounds__(BLOCK) void matvec_kernel(
    const float* __restrict__ mu, const float* __restrict__ A,
    const float* __restrict__ eps, const int* __restrict__ counts,
    const int* __restrict__ offsets, const int* __restrict__ list,
    float* __restrict__ out) {
    const int g = blockIdx.x / NCHUNK;
    const int c = blockIdx.x % NCHUNK;
    const int cnt = counts[g];
    const int off = offsets[g];
    const int d0 = threadIdx.x;          // 0..127
    const int d1 = threadIdx.x + 128;    // 128..255

    __shared__ float eps_s[S_TILE][DIM];
    __shared__ int bidx[S_TILE];

    const float* Ag = A + (size_t)g * (DIM * DIM);
    const float mu0 = mu[g * DIM + d0];
    const float mu1 = mu[g * DIM + d1];

    for (int t0 = c * S_TILE; t0 < cnt; t0 += NCHUNK * S_TILE) {
        const int ns = min(S_TILE, cnt - t0);

        __syncthreads();  // previous tile's LDS fully consumed
        if (threadIdx.x < S_TILE) {
            // clamp invalid slots to a valid sample so eps loads stay in-bounds
            int t = (threadIdx.x < ns) ? (t0 + threadIdx.x) : t0;
            bidx[threadIdx.x] = list[off + t];
        }
        __syncthreads();

        // stage eps tile: 8 rows x 64 float4; 128 threads -> 16 threads/row,
        // 4 float4 each, coalesced
        {
            int s = threadIdx.x >> 4;   // 0..7
            int l = threadIdx.x & 15;   // 0..15
            const float4* src = (const float4*)(eps + (size_t)bidx[s] * DIM);
            float4* dst = (float4*)(&eps_s[s][0]);
#pragma unroll
            for (int q = 0; q < 4; ++q) dst[l + 16 * q] = src[l + 16 * q];
        }
        __syncthreads();

        float acc0[S_TILE], acc1[S_TILE];
#pragma unroll
        for (int s = 0; s < S_TILE; ++s) {
            acc0[s] = 0.f;
            acc1[s] = 0.f;
        }

        const float4* A0 = (const float4*)(Ag + (size_t)d0 * DIM);
        const float4* A1 = (const float4*)(Ag + (size_t)d1 * DIM);

#pragma unroll 2
        for (int j4 = 0; j4 < DIM / 4; ++j4) {
            float4 a0 = A0[j4];
            float4 a1 = A1[j4];
#pragma unroll
            for (int s = 0; s < S_TILE; ++s) {
                float4 e = *(const float4*)(&eps_s[s][j4 * 4]);
                acc0[s] += a0.x * e.x + a0.y * e.y + a0.z * e.z + a0.w * e.w;
                acc1[s] += a1.x * e.x + a1.y * e.y + a1.z * e.z + a1.w * e.w;
            }
        }

        for (int s = 0; s < ns; ++s) {
            size_t ob = (size_t)bidx[s] * DIM;
            out[ob + d0] = acc0[s] + mu0;
            out[ob + d1] = acc1[s] + mu1;
        }
    }
}

extern "C" void kernel_launch(void* const* d_in, const int* in_sizes, int n_in,
                              void* d_out, int out_size, void* d_ws,
                              size_t ws_size, hipStream_t stream) {
    const float* mu  = (const float*)d_in[0];   // [NG, DIM]
    const float* A   = (const float*)d_in[1];   // [NG, DIM, DIM]
    const float* eps = (const float*)d_in[2];   // [B, DIM]
    const int*   k   = (const int*)d_in[3];     // [B] int32
    const int batch  = in_sizes[3];
    float* out = (float*)d_out;

    // workspace layout (ints): counts[NG] | offsets[NG] | pos[batch] | list[batch]
    int* ws      = (int*)d_ws;
    int* counts  = ws;
    int* offsets = ws + NG;
    int* pos     = ws + 2 * NG;
    int* list    = pos + batch;

    const int nb = (batch + 255) / 256;
    zero_counts_kernel<<<1, NG, 0, stream>>>(counts);
    count_pos_kernel<<<nb, 256, 0, stream>>>(k, counts, pos, batch);
    prefix_kernel<<<1, 1, 0, stream>>>(counts, offsets);
    scatter_kernel<<<nb, 256, 0, stream>>>(k, offsets, pos, list, batch);
    matvec_kernel<<<NG * NCHUNK, BLOCK, 0, stream>>>(mu, A, eps, counts,
                                                     offsets, list, out);
}

// Round 2
// 102.575 us; speedup vs baseline: 1.3359x; 1.3359x over previous
//
#include <hip/hip_runtime.h>

#define DIM 256
#define NG 64
#define NSLICE 4   // 64-dim output slices
#define NHALF 2    // batch halves (limits A re-read to 2x)
#define BLOCK 256
#define ST 8       // sample tile staged in LDS
#define MAXLIST 2048

// Block (g, slice, half): computes out[b][slice*64 .. slice*64+63] for all
// samples b in `half` of the batch with k[b]==g.
// Thread t: dd = t>>3 (0..31), q = t&7. Owns output dims (dbase+dd,
// dbase+32+dd), K-range q*32..q*32+31. A slice (64 floats) lives in VGPRs
// for the whole kernel — A is fetched exactly once per element per half.
// Per-sample partial dot is reduced over the 8 q-lanes via __shfl_xor.

__global__ __launch_bounds__(BLOCK) void fused_kernel(
    const float* __restrict__ mu, const float* __restrict__ A,
    const float* __restrict__ eps, const int* __restrict__ k,
    float* __restrict__ out, int batch) {

    const int g     = blockIdx.x >> 3;
    const int slice = (blockIdx.x >> 1) & (NSLICE - 1);
    const int half  = blockIdx.x & (NHALF - 1);
    const int t  = threadIdx.x;
    const int dd = t >> 3;   // 0..31
    const int q  = t & 7;    // 0..7
    const int dbase = slice * 64;
    const int d0 = dbase + dd;
    const int d1 = dbase + 32 + dd;

    __shared__ int   list[MAXLIST];
    __shared__ int   lcount;
    __shared__ int   bidx[ST];
    // eps rows stored as 4 segments of 68 floats (64 data + 4 pad) so the 8
    // distinct per-wave LDS read addresses are only 2-way on banks (free).
    __shared__ float eps_s[ST][4 * 68];

    if (t == 0) lcount = 0;
    __syncthreads();

    // ---- scan this half of k, append matching sample ids to LDS list ----
    {
        const int hn = batch / NHALF;          // 2048
        const int hb = half * hn;
        const int4* k4 = (const int4*)(k + hb);
        const int iters = hn / 4 / BLOCK;      // 2
        for (int r = 0; r < iters; ++r) {
            int idx = t + r * BLOCK;
            int4 kv = k4[idx];
            int b0 = hb + idx * 4;
            if (kv.x == g) list[atomicAdd(&lcount, 1)] = b0;
            if (kv.y == g) list[atomicAdd(&lcount, 1)] = b0 + 1;
            if (kv.z == g) list[atomicAdd(&lcount, 1)] = b0 + 2;
            if (kv.w == g) list[atomicAdd(&lcount, 1)] = b0 + 3;
        }
    }

    // ---- load A slices into registers (one-time, stays resident) ----
    float4 a0[8], a1[8];
    {
        const float4* A0 = (const float4*)(A + ((size_t)g * DIM + d0) * DIM + q * 32);
        const float4* A1 = (const float4*)(A + ((size_t)g * DIM + d1) * DIM + q * 32);
#pragma unroll
        for (int i = 0; i < 8; ++i) { a0[i] = A0[i]; a1[i] = A1[i]; }
    }
    const float mu0 = mu[g * DIM + d0];
    const float mu1 = mu[g * DIM + d1];

    __syncthreads();
    const int n = lcount;

    for (int t0 = 0; t0 < n; t0 += ST) {
        const int ns = min(ST, n - t0);
        __syncthreads();  // previous tile's eps_s/bidx fully consumed
        if (t < ST) bidx[t] = list[t0 + ((t < ns) ? t : 0)];
        __syncthreads();

        // stage eps tile: 8 rows x 64 float4, coalesced, segmented layout
#pragma unroll
        for (int r = 0; r < (ST * 64) / BLOCK; ++r) {  // 2 iters
            int idx = t + r * BLOCK;       // 0..511
            int s = idx >> 6;              // row 0..7
            int w = idx & 63;              // float4 index within row
            float4 v = ((const float4*)(eps + (size_t)bidx[s] * DIM))[w];
            int seg = w >> 4;
            int within = (w & 15) * 4;
            *(float4*)(&eps_s[s][seg * 68 + within]) = v;
        }
        __syncthreads();

        for (int s = 0; s < ns; ++s) {
            const float* ep = &eps_s[s][(q >> 1) * 68 + (q & 1) * 32];
            float acc0 = 0.f, acc1 = 0.f;
#pragma unroll
            for (int i = 0; i < 8; ++i) {
                float4 e = *(const float4*)(ep + i * 4);
                acc0 += a0[i].x * e.x + a0[i].y * e.y + a0[i].z * e.z + a0[i].w * e.w;
                acc1 += a1[i].x * e.x + a1[i].y * e.y + a1[i].z * e.z + a1[i].w * e.w;
            }
            // reduce partials over q (lane bits 0..2)
            acc0 += __shfl_xor(acc0, 1);
            acc0 += __shfl_xor(acc0, 2);
            acc0 += __shfl_xor(acc0, 4);
            acc1 += __shfl_xor(acc1, 1);
            acc1 += __shfl_xor(acc1, 2);
            acc1 += __shfl_xor(acc1, 4);
            if (q == 0) {
                size_t ob = (size_t)bidx[s] * DIM;
                out[ob + d0] = acc0 + mu0;
                out[ob + d1] = acc1 + mu1;
            }
        }
    }
}

extern "C" void kernel_launch(void* const* d_in, const int* in_sizes, int n_in,
                              void* d_out, int out_size, void* d_ws,
                              size_t ws_size, hipStream_t stream) {
    const float* mu  = (const float*)d_in[0];   // [NG, DIM]
    const float* A   = (const float*)d_in[1];   // [NG, DIM, DIM]
    const float* eps = (const float*)d_in[2];   // [B, DIM]
    const int*   k   = (const int*)d_in[3];     // [B] int32
    const int batch  = in_sizes[3];
    float* out = (float*)d_out;

    fused_kernel<<<NG * NSLICE * NHALF, BLOCK, 0, stream>>>(mu, A, eps, k,
                                                            out, batch);
}

// Round 3
// 98.709 us; speedup vs baseline: 1.3882x; 1.0392x over previous
//
#include <hip/hip_runtime.h>

#define DIM 256
#define NG 64
#define NSLICE 4   // 64-dim output slices
#define NHALF 2    // batch halves (A re-read 2x; 2nd read is L3-resident)
#define BLOCK 256
#define ST 8       // sample tile staged in LDS
#define MAXLIST 2048
#define SEG 68     // 64 data floats + 4 pad per K-segment (2-way banks = free)

// Block (g, slice, half): out[b][slice*64 .. +63] for samples b in `half`
// with k[b]==g. Thread t: dd=t>>3 (0..31), q=t&7. Owns dims (d0,d1) =
// (slice*64+dd, +32), K-range q*32..q*32+31; A slice (64 floats) register-
// resident. Per-sample partials reduced over q via 3 shuffles (parity trick).

__device__ __forceinline__ void compute_sample(
    int s, const float (*eps_s)[4 * SEG], const int* bidx_s,
    const float4* a0, const float4* a1, float mu0, float mu1,
    int q, int d0, int d1, float* __restrict__ out) {
    const float* ep = &eps_s[s][(q >> 1) * SEG + (q & 1) * 32];
    float acc0 = 0.f, acc1 = 0.f;
#pragma unroll
    for (int i = 0; i < 8; ++i) {
        float4 e = *(const float4*)(ep + i * 4);
        acc0 += a0[i].x * e.x + a0[i].y * e.y + a0[i].z * e.z + a0[i].w * e.w;
        acc1 += a1[i].x * e.x + a1[i].y * e.y + a1[i].z * e.z + a1[i].w * e.w;
    }
    // parity-swap reduce: odd lanes send acc0, even send acc1
    float r  = (q & 1) ? acc0 : acc1;
    float r2 = __shfl_xor(r, 1);
    float z  = ((q & 1) ? acc1 : acc0) + r2;
    z += __shfl_xor(z, 2);
    z += __shfl_xor(z, 4);
    if (q < 2) {  // q==0 holds sum(acc0) -> d0; q==1 holds sum(acc1) -> d1
        size_t ob = (size_t)bidx_s[s] * DIM;
        out[ob + (q ? d1 : d0)] = z + (q ? mu1 : mu0);
    }
}

__global__ __launch_bounds__(BLOCK) void fused_kernel(
    const float* __restrict__ mu, const float* __restrict__ A,
    const float* __restrict__ eps, const int* __restrict__ k,
    float* __restrict__ out, int batch) {

    const int g     = blockIdx.x >> 3;
    const int slice = (blockIdx.x >> 1) & (NSLICE - 1);
    const int half  = blockIdx.x & (NHALF - 1);
    const int t  = threadIdx.x;
    const int dd = t >> 3;   // 0..31
    const int q  = t & 7;    // 0..7
    const int d0 = slice * 64 + dd;
    const int d1 = d0 + 32;

    __shared__ int   list[MAXLIST];
    __shared__ int   lcount;
    __shared__ int   bidx_s[ST];
    __shared__ float eps_s[ST][4 * SEG];

    if (t == 0) lcount = 0;
    __syncthreads();

    // ---- scan this half of k, append matching sample ids ----
    {
        const int hn = batch / NHALF;
        const int hb = half * hn;
        const int4* k4 = (const int4*)(k + hb);
        const int iters = hn / 4 / BLOCK;
        for (int r = 0; r < iters; ++r) {
            int idx = t + r * BLOCK;
            int4 kv = k4[idx];
            int b0 = hb + idx * 4;
            if (kv.x == g) list[atomicAdd(&lcount, 1)] = b0;
            if (kv.y == g) list[atomicAdd(&lcount, 1)] = b0 + 1;
            if (kv.z == g) list[atomicAdd(&lcount, 1)] = b0 + 2;
            if (kv.w == g) list[atomicAdd(&lcount, 1)] = b0 + 3;
        }
    }

    // ---- A slices into registers (independent of scan; overlaps) ----
    float4 a0[8], a1[8];
    {
        const float4* A0 = (const float4*)(A + ((size_t)g * DIM + d0) * DIM + q * 32);
        const float4* A1 = (const float4*)(A + ((size_t)g * DIM + d1) * DIM + q * 32);
#pragma unroll
        for (int i = 0; i < 8; ++i) { a0[i] = A0[i]; a1[i] = A1[i]; }
    }
    const float mu0 = mu[g * DIM + d0];
    const float mu1 = mu[g * DIM + d1];

    __syncthreads();
    const int n = lcount;
    if (n == 0) return;  // uniform per block: barrier-safe

    // staging role: thread stages float4 `w` of rows s0 and s0+4
    const int s0 = t >> 6, w = t & 63;
    const int seg = w >> 4, within = (w & 15) * 4;
    const float4* eps4 = (const float4*)eps;

    // prologue prefetch (list is stable after the barrier above)
    float4 pf0, pf1;
    {
        int bA = list[min(s0, n - 1)];
        int bB = list[min(s0 + 4, n - 1)];
        pf0 = eps4[(size_t)bA * 64 + w];
        pf1 = eps4[(size_t)bB * 64 + w];
    }

    for (int t0 = 0; t0 < n; t0 += ST) {
        const int ns = min(ST, n - t0);
        __syncthreads();  // previous tile fully consumed
        *(float4*)(&eps_s[s0][seg * SEG + within])     = pf0;
        *(float4*)(&eps_s[s0 + 4][seg * SEG + within]) = pf1;
        if (t < ST) bidx_s[t] = list[min(t0 + t, n - 1)];
        __syncthreads();

        // prefetch next tile; loads stay in flight across the compute below
        if (t0 + ST < n) {
            int bA = list[min(t0 + ST + s0, n - 1)];
            int bB = list[min(t0 + ST + s0 + 4, n - 1)];
            pf0 = eps4[(size_t)bA * 64 + w];
            pf1 = eps4[(size_t)bB * 64 + w];
        }

        if (ns == ST) {
#pragma unroll 4
            for (int s = 0; s < ST; ++s)
                compute_sample(s, eps_s, bidx_s, a0, a1, mu0, mu1, q, d0, d1, out);
        } else {
            for (int s = 0; s < ns; ++s)
                compute_sample(s, eps_s, bidx_s, a0, a1, mu0, mu1, q, d0, d1, out);
        }
    }
}

extern "C" void kernel_launch(void* const* d_in, const int* in_sizes, int n_in,
                              void* d_out, int out_size, void* d_ws,
                              size_t ws_size, hipStream_t stream) {
    const float* mu  = (const float*)d_in[0];   // [NG, DIM]
    const float* A   = (const float*)d_in[1];   // [NG, DIM, DIM]
    const float* eps = (const float*)d_in[2];   // [B, DIM]
    const int*   k   = (const int*)d_in[3];     // [B] int32
    const int batch  = in_sizes[3];
    float* out = (float*)d_out;

    fused_kernel<<<NG * NSLICE * NHALF, BLOCK, 0, stream>>>(mu, A, eps, k,
                                                            out, batch);
}

// Round 4
// 96.531 us; speedup vs baseline: 1.4195x; 1.0226x over previous
//
#include <hip/hip_runtime.h>

#define DIM 256
#define NG 64
#define NSLICE 4   // 64-dim output slices
#define NQ 4       // batch quarters (A re-read 4x, L2/L3-served; 2x occupancy)
#define BLOCK 256
#define ST 8       // sample tile staged in LDS
#define MAXLIST 1024
#define SEG 68     // 64 data floats + 4 pad per K-segment (2-way banks = free)

// Block (g, slice, quarter): out[b][slice*64 .. +63] for samples b in
// `quarter` with k[b]==g. Thread t: dd=t>>3 (0..31), q=t&7. Owns dims
// (d0,d1) = (slice*64+dd, +32), K-range q*32..+31; A slice (64 floats)
// register-resident. Partials reduced over q via 3 shuffles (parity trick).
// __launch_bounds__(256,4): 4 waves/EU -> 4 blocks/CU co-resident.

__device__ __forceinline__ void compute_sample(
    int s, const float (*eps_s)[4 * SEG], const int* bidx_s,
    const float4* a0, const float4* a1, float mu0, float mu1,
    int q, int d0, int d1, float* __restrict__ out) {
    const float* ep = &eps_s[s][(q >> 1) * SEG + (q & 1) * 32];
    float acc0 = 0.f, acc1 = 0.f;
#pragma unroll
    for (int i = 0; i < 8; ++i) {
        float4 e = *(const float4*)(ep + i * 4);
        acc0 += a0[i].x * e.x + a0[i].y * e.y + a0[i].z * e.z + a0[i].w * e.w;
        acc1 += a1[i].x * e.x + a1[i].y * e.y + a1[i].z * e.z + a1[i].w * e.w;
    }
    // parity-swap reduce: odd lanes send acc0, even send acc1
    float r  = (q & 1) ? acc0 : acc1;
    float r2 = __shfl_xor(r, 1);
    float z  = ((q & 1) ? acc1 : acc0) + r2;
    z += __shfl_xor(z, 2);
    z += __shfl_xor(z, 4);
    if (q < 2) {  // q==0 holds sum(acc0) -> d0; q==1 holds sum(acc1) -> d1
        size_t ob = (size_t)bidx_s[s] * DIM;
        out[ob + (q ? d1 : d0)] = z + (q ? mu1 : mu0);
    }
}

__global__ __launch_bounds__(BLOCK, 4) void fused_kernel(
    const float* __restrict__ mu, const float* __restrict__ A,
    const float* __restrict__ eps, const int* __restrict__ k,
    float* __restrict__ out, int batch) {

    const int g     = blockIdx.x >> 4;
    const int slice = (blockIdx.x >> 2) & (NSLICE - 1);
    const int quart = blockIdx.x & (NQ - 1);
    const int t  = threadIdx.x;
    const int dd = t >> 3;   // 0..31
    const int q  = t & 7;    // 0..7
    const int d0 = slice * 64 + dd;
    const int d1 = d0 + 32;

    __shared__ int   list[MAXLIST];
    __shared__ int   lcount;
    __shared__ int   bidx_s[ST];
    __shared__ float eps_s[ST][4 * SEG];

    if (t == 0) lcount = 0;
    __syncthreads();

    // ---- scan this quarter of k: one int4 per thread ----
    {
        const int qn = batch / NQ;            // 1024
        const int qb = quart * qn;
        int4 kv = ((const int4*)(k + qb))[t];
        int b0 = qb + t * 4;
        if (kv.x == g) list[atomicAdd(&lcount, 1)] = b0;
        if (kv.y == g) list[atomicAdd(&lcount, 1)] = b0 + 1;
        if (kv.z == g) list[atomicAdd(&lcount, 1)] = b0 + 2;
        if (kv.w == g) list[atomicAdd(&lcount, 1)] = b0 + 3;
    }

    // ---- A slices into registers (independent of scan; overlaps) ----
    float4 a0[8], a1[8];
    {
        const float4* A0 = (const float4*)(A + ((size_t)g * DIM + d0) * DIM + q * 32);
        const float4* A1 = (const float4*)(A + ((size_t)g * DIM + d1) * DIM + q * 32);
#pragma unroll
        for (int i = 0; i < 8; ++i) { a0[i] = A0[i]; a1[i] = A1[i]; }
    }
    const float mu0 = mu[g * DIM + d0];
    const float mu1 = mu[g * DIM + d1];

    __syncthreads();
    const int n = lcount;
    if (n == 0) return;  // uniform per block: barrier-safe

    // staging role: thread stages float4 `w` of rows s0 and s0+4
    const int s0 = t >> 6, w = t & 63;
    const int seg = w >> 4, within = (w & 15) * 4;
    const float4* eps4 = (const float4*)eps;

    // prologue prefetch (list is stable after the barrier above)
    float4 pf0, pf1;
    {
        int bA = list[min(s0, n - 1)];
        int bB = list[min(s0 + 4, n - 1)];
        pf0 = eps4[(size_t)bA * 64 + w];
        pf1 = eps4[(size_t)bB * 64 + w];
    }

    for (int t0 = 0; t0 < n; t0 += ST) {
        const int ns = min(ST, n - t0);
        __syncthreads();  // previous tile fully consumed
        *(float4*)(&eps_s[s0][seg * SEG + within])     = pf0;
        *(float4*)(&eps_s[s0 + 4][seg * SEG + within]) = pf1;
        if (t < ST) bidx_s[t] = list[min(t0 + t, n - 1)];
        __syncthreads();

        // prefetch next tile; loads stay in flight across the compute below
        if (t0 + ST < n) {
            int bA = list[min(t0 + ST + s0, n - 1)];
            int bB = list[min(t0 + ST + s0 + 4, n - 1)];
            pf0 = eps4[(size_t)bA * 64 + w];
            pf1 = eps4[(size_t)bB * 64 + w];
        }

        if (ns == ST) {
#pragma unroll 4
            for (int s = 0; s < ST; ++s)
                compute_sample(s, eps_s, bidx_s, a0, a1, mu0, mu1, q, d0, d1, out);
        } else {
            for (int s = 0; s < ns; ++s)
                compute_sample(s, eps_s, bidx_s, a0, a1, mu0, mu1, q, d0, d1, out);
        }
    }
}

extern "C" void kernel_launch(void* const* d_in, const int* in_sizes, int n_in,
                              void* d_out, int out_size, void* d_ws,
                              size_t ws_size, hipStream_t stream) {
    const float* mu  = (const float*)d_in[0];   // [NG, DIM]
    const float* A   = (const float*)d_in[1];   // [NG, DIM, DIM]
    const float* eps = (const float*)d_in[2];   // [B, DIM]
    const int*   k   = (const int*)d_in[3];     // [B] int32
    const int batch  = in_sizes[3];
    float* out = (float*)d_out;

    fused_kernel<<<NG * NSLICE * NQ, BLOCK, 0, stream>>>(mu, A, eps, k,
                                                         out, batch);
}